// Round 1
// baseline (204.621 us; speedup 1.0000x reference)
//
#include <hip/hip_runtime.h>

// GLA forward, chunked. T=2048, B=8, IN=512, DV=512, NK=128, CHUNK=128, NCH=16.
// Round 5: (1) proj_mfma LDS bank-conflict fix via both-sides XOR swizzle
// (pre-swizzled global source for global_load_lds + swizzled ds_read slot);
// (2) scan_state vectorized x4 (8B/lane); (3) scan_cp spread to 256 blocks
// x 64 threads (1 wave/CU across all 256 CUs).
//
// Layouts (cb = c*8+b, r = t_glob*8+b):
//   a_buf  fp32 [r][128]
//   k_raw/q_raw bf16 [r][128]
//   qb/kbs bf16 [r][128]          (q~ = q*cp, k~ = k/(cp+eps))
//   kt     bf16 [cb*128 + n][s]   (k~ transposed)
//   vt     bf16 [cb*512 + d][s]
//   Gt     bf16 [cb*512 + d][n]   (scan input, overlays xb)
//   St     bf16 [cb*512 + d][n]   (S_prev per chunk)

#define EPSV 1e-8f

typedef __bf16 bf16x8 __attribute__((ext_vector_type(8)));
typedef __bf16 bf16x4 __attribute__((ext_vector_type(4)));
typedef float f32x4 __attribute__((ext_vector_type(4)));

__device__ __forceinline__ void async_copy16(const void* g, void* l) {
  __builtin_amdgcn_global_load_lds(
      (const __attribute__((address_space(1))) void*)g,
      (__attribute__((address_space(3))) void*)l, 16, 0, 0);
}

// ---- fp32 -> bf16 conversion (8 elems/thread) ----
__global__ __launch_bounds__(256) void conv_bf16(const float* __restrict__ src,
                                                 __bf16* __restrict__ dst) {
  long i = ((long)blockIdx.x * 256 + threadIdx.x) * 8;
  float4 f0 = *(const float4*)(src + i);
  float4 f1 = *(const float4*)(src + i + 4);
  bf16x8 h;
  h[0] = (__bf16)f0.x; h[1] = (__bf16)f0.y; h[2] = (__bf16)f0.z; h[3] = (__bf16)f0.w;
  h[4] = (__bf16)f1.x; h[5] = (__bf16)f1.y; h[6] = (__bf16)f1.z; h[7] = (__bf16)f1.w;
  *(bf16x8*)(dst + i) = h;
}

// ---- concat Wv|Wk|Wq|Wa into bf16 [896][512] ----
__global__ __launch_bounds__(256) void conv_w(const float* __restrict__ Wv,
                                              const float* __restrict__ Wk,
                                              const float* __restrict__ Wq,
                                              const float* __restrict__ Wa,
                                              __bf16* __restrict__ dst) {
  long i = ((long)blockIdx.x * 256 + threadIdx.x) * 8;
  int row = (int)(i >> 9);
  int col = (int)(i & 511);
  const float* src;
  if (row < 512)      src = Wv + (long)row * 512 + col;
  else if (row < 640) src = Wk + (long)(row - 512) * 512 + col;
  else if (row < 768) src = Wq + (long)(row - 640) * 512 + col;
  else                src = Wa + (long)(row - 768) * 512 + col;
  float4 f0 = *(const float4*)(src);
  float4 f1 = *(const float4*)(src + 4);
  bf16x8 h;
  h[0] = (__bf16)f0.x; h[1] = (__bf16)f0.y; h[2] = (__bf16)f0.z; h[3] = (__bf16)f0.w;
  h[4] = (__bf16)f1.x; h[5] = (__bf16)f1.y; h[6] = (__bf16)f1.z; h[7] = (__bf16)f1.w;
  *(bf16x8*)(dst + i) = h;
}

// ---- K1: projection GEMM, bf16 MFMA. grid (128 Mtiles, 7 Ntiles) ----
// nt 0..3 -> vt (bf16, LDS-transposed); 4 -> k_raw; 5 -> q_raw; 6 -> alpha fp32.
// LDS tiles are [128 rows][4 slots of 16B] with slot ^= (row>>1)&3 swizzle.
// global_load_lds writes linearly (row, phys-slot lc); the SOURCE column-group
// is pre-permuted (lc ^ (lr>>1)&3) so a matching XOR on the ds_read slot
// recovers logical data and spreads 8 consecutive rows across 8 distinct
// 4-bank groups (2-way residual aliasing = free).
__global__ __launch_bounds__(256) void proj_mfma(
    const __bf16* __restrict__ xb, const __bf16* __restrict__ wcat,
    const float* __restrict__ bv, const float* __restrict__ bk,
    const float* __restrict__ bq, const float* __restrict__ ba,
    __bf16* __restrict__ vt, __bf16* __restrict__ kout,
    __bf16* __restrict__ qout, float* __restrict__ aout) {
  // 34816 B: staging (16 KB) first, transpose buffer reuses whole block
  __shared__ __attribute__((aligned(16))) char smem[128 * 136 * 2];
  __bf16* a_sm = (__bf16*)smem;
  __bf16* b_sm = a_sm + 128 * 32;
  __bf16* tr   = (__bf16*)smem;      // reused after K-loop (post-barrier)

  int tid = threadIdx.x;
  int lane = tid & 63, wave = tid >> 6;
  int mt = blockIdx.x, nt = blockIdx.y;
  int wr = wave >> 1, wcol = wave & 1;

  const __bf16* xtile = xb + (long)mt * 128 * 512;
  const __bf16* wtile = wcat + (long)nt * 128 * 512;

  f32x4 acc[4][4] = {};
  int lr = lane >> 2, lc = lane & 3;
  int l15 = lane & 15, qd = lane >> 4;
  // source-side swizzle: physical slot lc holds logical col-group lc^((lr>>1)&3)
  int slsrc = (lc ^ ((lr >> 1) & 3)) * 8;
  // read-side swizzle: logical slot qd lives at physical slot qd^((l15>>1)&3)
  int frd = (l15 >> 1) & 3;

  for (int k0 = 0; k0 < 512; k0 += 32) {
#pragma unroll
    for (int h = 0; h < 2; ++h) {
      int q = wave * 2 + h;
      int row = q * 16 + lr;
      async_copy16(xtile + (long)row * 512 + k0 + slsrc, &a_sm[q * 512]);
      async_copy16(wtile + (long)row * 512 + k0 + slsrc, &b_sm[q * 512]);
    }
    __syncthreads();
    bf16x8 af[4], bfr[4];
#pragma unroll
    for (int t = 0; t < 4; ++t) {
      af[t]  = *(const bf16x8*)&a_sm[(wr * 64 + t * 16 + l15) * 32 + (qd ^ frd) * 8];
      bfr[t] = *(const bf16x8*)&b_sm[(wcol * 64 + t * 16 + l15) * 32 + (qd ^ frd) * 8];
    }
#pragma unroll
    for (int i = 0; i < 4; ++i)
#pragma unroll
      for (int j = 0; j < 4; ++j)
        acc[i][j] = __builtin_amdgcn_mfma_f32_16x16x32_bf16(af[i], bfr[j], acc[i][j], 0, 0, 0);
    __syncthreads();
  }

  if (nt < 4) {
    // v path: bias, cast bf16, transpose in LDS, write vt coalesced-ish.
    // tr layout: [d(128)][b*16 + t_l] pitch 136.
    const float* bias = bv + nt * 128;
#pragma unroll
    for (int i = 0; i < 4; ++i)
#pragma unroll
      for (int j = 0; j < 4; ++j) {
        int col = wcol * 64 + j * 16 + l15;
        float bz = bias[col];
#pragma unroll
        for (int r = 0; r < 4; ++r) {
          int row = wr * 64 + i * 16 + qd * 4 + r;   // row = t_l*8 + b
          tr[col * 136 + (row & 7) * 16 + (row >> 3)] = (__bf16)(acc[i][j][r] + bz);
        }
      }
    __syncthreads();
    int cbase = (mt >> 3) * 8;        // chunk c * 8
    int s0 = (mt & 7) * 16;           // s offset within chunk
#pragma unroll
    for (int it = 0; it < 4; ++it) {
      int p = it * 256 + tid;         // 1024 (d,b) pairs
      int d = p & 127, b = p >> 7;
      bf16x8 u0 = *(const bf16x8*)&tr[d * 136 + b * 16];
      bf16x8 u1 = *(const bf16x8*)&tr[d * 136 + b * 16 + 8];
      __bf16* dst = vt + ((long)(cbase + b) * 512 + nt * 128 + d) * 128 + s0;
      *(bf16x8*)dst = u0;
      *(bf16x8*)(dst + 8) = u1;
    }
    return;
  }

  const float* bias; bool sig = false;
  __bf16* dstb = nullptr; float* dstf = nullptr;
  if (nt == 4)      { bias = bk; dstb = kout; }
  else if (nt == 5) { bias = bq; dstb = qout; }
  else              { bias = ba; dstf = aout; sig = true; }

#pragma unroll
  for (int i = 0; i < 4; ++i)
#pragma unroll
    for (int j = 0; j < 4; ++j) {
      int col = wcol * 64 + j * 16 + l15;
      float bz = bias[col];
#pragma unroll
      for (int r = 0; r < 4; ++r) {
        int row = wr * 64 + i * 16 + qd * 4 + r;
        float z = acc[i][j][r] + bz;
        long addr = ((long)mt * 128 + row) * 128 + col;
        if (sig) dstf[addr] = 1.f / (1.f + __expf(-z));
        else     dstb[addr] = (__bf16)z;
      }
    }
}

// ---- scan_cp: cumprod; emits qb/kbs bf16 natural, kt transposed, cpend ----
// 256 blocks x 64 threads: one wave per CU across the whole chip (was 64x256,
// which left 192 CUs idle on a latency-bound serial-chain kernel).
__global__ __launch_bounds__(64) void scan_cp(const float* __restrict__ a,
                                              const __bf16* __restrict__ k,
                                              const __bf16* __restrict__ q,
                                              __bf16* __restrict__ kbs,
                                              __bf16* __restrict__ qb,
                                              __bf16* __restrict__ kt,
                                              float* __restrict__ cpend) {
  int idx = blockIdx.x * 64 + threadIdx.x;  // 16384 = 16c*8b*128n
  int n = idx & 127;
  int b = (idx >> 7) & 7;
  int c = idx >> 10;
  long base = ((long)c * 1024 + b) * 128 + n;
  float cp = 1.f;
  __bf16 ktbuf[128];
#pragma unroll
  for (int tt = 0; tt < 128; ++tt) {
    long off = base + (long)tt * 1024;
    float av = fmaxf(a[off], EPSV);
    cp *= av;
    float kk = (float)k[off] / (cp + EPSV);
    float qq = (float)q[off] * cp;
    __bf16 kh = (__bf16)kk;
    kbs[off] = kh;
    qb[off] = (__bf16)qq;
    ktbuf[tt] = kh;
  }
  cpend[(c * 8 + b) * 128 + n] = cp;
  __bf16* dst = kt + ((long)((c * 8 + b) * 128 + n)) * 128;
#pragma unroll
  for (int i = 0; i < 16; ++i) {
    bf16x8 h;
#pragma unroll
    for (int j = 0; j < 8; ++j) h[j] = ktbuf[i * 8 + j];
    *(bf16x8*)(dst + i * 8) = h;
  }
}

// ---- gmm: Gt[d,n] = cpend[n] * sum_s vt[d,s]*kt[n,s].  grid 512 = cb*4+dt ----
__global__ __launch_bounds__(256) void gmm(const __bf16* __restrict__ vt,
                                           const __bf16* __restrict__ kt,
                                           const float* __restrict__ cpend,
                                           __bf16* __restrict__ Gt) {
  int tid = threadIdx.x, lane = tid & 63, wave = tid >> 6;
  int wr = wave >> 1, wc = wave & 1;
  int l15 = lane & 15, qd = lane >> 4;
  int cb = blockIdx.x >> 2, dt = blockIdx.x & 3;
  const __bf16* vbase = vt + ((long)cb * 512 + dt * 128) * 128;
  const __bf16* kbase = kt + (long)cb * 16384;
  f32x4 acc[4][4] = {};
#pragma unroll
  for (int kk = 0; kk < 4; ++kk) {
    int k0 = kk * 32;
    bf16x8 af[4], bfr[4];
#pragma unroll
    for (int i = 0; i < 4; ++i)
      af[i] = *(const bf16x8*)(vbase + (long)(wr * 64 + i * 16 + l15) * 128 + k0 + qd * 8);
#pragma unroll
    for (int j = 0; j < 4; ++j)
      bfr[j] = *(const bf16x8*)(kbase + (long)(wc * 64 + j * 16 + l15) * 128 + k0 + qd * 8);
#pragma unroll
    for (int i = 0; i < 4; ++i)
#pragma unroll
      for (int j = 0; j < 4; ++j)
        acc[i][j] = __builtin_amdgcn_mfma_f32_16x16x32_bf16(af[i], bfr[j], acc[i][j], 0, 0, 0);
  }
  float ce[4];
#pragma unroll
  for (int j = 0; j < 4; ++j) ce[j] = cpend[cb * 128 + wc * 64 + j * 16 + l15];
#pragma unroll
  for (int i = 0; i < 4; ++i)
#pragma unroll
    for (int j = 0; j < 4; ++j) {
      int col = wc * 64 + j * 16 + l15;
#pragma unroll
      for (int r = 0; r < 4; ++r) {
        int row = wr * 64 + i * 16 + qd * 4 + r;
        Gt[((long)cb * 512 + dt * 128 + row) * 128 + col] = (__bf16)(acc[i][j][r] * ce[j]);
      }
    }
}

// ---- scan_state: fp32 scan over chunks on Gt(bf16); emits St bf16 ----
// vectorized x4: 8B loads/stores per lane (was scalar 2B).
__global__ __launch_bounds__(256) void scan_state(const __bf16* __restrict__ Gt,
                                                  const float* __restrict__ cpend,
                                                  __bf16* __restrict__ St) {
  long e = ((long)blockIdx.x * 256 + threadIdx.x) * 4;  // 524288 = 8b*512d*128n
  int n0 = (int)(e & 127);
  int b = (int)(e >> 16);
  float4 S = {0.f, 0.f, 0.f, 0.f};
#pragma unroll
  for (int c = 0; c < 16; ++c) {
    long idx = (long)c * 524288 + e;
    bf16x4 g = *(const bf16x4*)(Gt + idx);
    bf16x4 sv;
    sv[0] = (__bf16)S.x; sv[1] = (__bf16)S.y;
    sv[2] = (__bf16)S.z; sv[3] = (__bf16)S.w;
    *(bf16x4*)(St + idx) = sv;
    const float4 cp = *(const float4*)(cpend + (c * 8 + b) * 128 + n0);
    S.x = (float)g[0] + S.x * cp.x;
    S.y = (float)g[1] + S.y * cp.y;
    S.z = (float)g[2] + S.z * cp.z;
    S.w = (float)g[3] + S.w * cp.w;
  }
}

// ---- ymm: y^T[d,t] = sum_s vt[d,s]*A[t,s] + sum_n St[d,n]*qb[t,n] ----
__global__ __launch_bounds__(256) void ymm(const __bf16* __restrict__ qb,
                                           const __bf16* __restrict__ kbs,
                                           const __bf16* __restrict__ vt,
                                           const __bf16* __restrict__ St,
                                           float* __restrict__ out) {
  __shared__ __bf16 A_lds[128 * 136];
  int tid = threadIdx.x, lane = tid & 63, wave = tid >> 6;
  int wr = wave >> 1, wc = wave & 1;
  int l15 = lane & 15, qd = lane >> 4;
  int cb = blockIdx.x >> 2, dt = blockIdx.x & 3;
  int c = cb >> 3, b = cb & 7;
  const __bf16* qbase = qb + ((long)c * 1024 + b) * 128;
  const __bf16* kbase = kbs + ((long)c * 1024 + b) * 128;

  {
    f32x4 accA[4][4] = {};
#pragma unroll
    for (int kk = 0; kk < 4; ++kk) {
      int k0 = kk * 32;
      bf16x8 af[4], bfr[4];
#pragma unroll
      for (int i = 0; i < 4; ++i)
        af[i] = *(const bf16x8*)(qbase + (long)(wr * 64 + i * 16 + l15) * 1024 + k0 + qd * 8);
#pragma unroll
      for (int j = 0; j < 4; ++j)
        bfr[j] = *(const bf16x8*)(kbase + (long)(wc * 64 + j * 16 + l15) * 1024 + k0 + qd * 8);
#pragma unroll
      for (int i = 0; i < 4; ++i)
#pragma unroll
        for (int j = 0; j < 4; ++j)
          accA[i][j] = __builtin_amdgcn_mfma_f32_16x16x32_bf16(af[i], bfr[j], accA[i][j], 0, 0, 0);
    }
#pragma unroll
    for (int i = 0; i < 4; ++i)
#pragma unroll
      for (int j = 0; j < 4; ++j) {
        int s = wc * 64 + j * 16 + l15;
#pragma unroll
        for (int r = 0; r < 4; ++r) {
          int t = wr * 64 + i * 16 + qd * 4 + r;
          A_lds[t * 136 + s] = (s <= t) ? (__bf16)accA[i][j][r] : (__bf16)0.f;
        }
      }
  }
  __syncthreads();

  f32x4 acc[4][4] = {};
  const __bf16* vbase = vt + ((long)cb * 512 + dt * 128) * 128;
  const __bf16* sbase = St + ((long)cb * 512 + dt * 128) * 128;
#pragma unroll
  for (int kk = 0; kk < 4; ++kk) {
    int k0 = kk * 32;
    bf16x8 af[4], bfr[4];
#pragma unroll
    for (int i = 0; i < 4; ++i)
      af[i] = *(const bf16x8*)(vbase + (long)(wr * 64 + i * 16 + l15) * 128 + k0 + qd * 8);
#pragma unroll
    for (int j = 0; j < 4; ++j)
      bfr[j] = *(const bf16x8*)&A_lds[(wc * 64 + j * 16 + l15) * 136 + k0 + qd * 8];
#pragma unroll
    for (int i = 0; i < 4; ++i)
#pragma unroll
      for (int j = 0; j < 4; ++j)
        acc[i][j] = __builtin_amdgcn_mfma_f32_16x16x32_bf16(af[i], bfr[j], acc[i][j], 0, 0, 0);
  }
#pragma unroll
  for (int kk = 0; kk < 4; ++kk) {
    int k0 = kk * 32;
    bf16x8 af[4], bfr[4];
#pragma unroll
    for (int i = 0; i < 4; ++i)
      af[i] = *(const bf16x8*)(sbase + (long)(wr * 64 + i * 16 + l15) * 128 + k0 + qd * 8);
#pragma unroll
    for (int j = 0; j < 4; ++j)
      bfr[j] = *(const bf16x8*)(qbase + (long)(wc * 64 + j * 16 + l15) * 1024 + k0 + qd * 8);
#pragma unroll
    for (int i = 0; i < 4; ++i)
#pragma unroll
      for (int j = 0; j < 4; ++j)
        acc[i][j] = __builtin_amdgcn_mfma_f32_16x16x32_bf16(af[i], bfr[j], acc[i][j], 0, 0, 0);
  }

#pragma unroll
  for (int i = 0; i < 4; ++i)
#pragma unroll
    for (int j = 0; j < 4; ++j) {
      int colt = wc * 64 + j * 16 + l15;
      long addr = ((long)(c * 128 + colt) * 8 + b) * 512 + dt * 128 + wr * 64 + i * 16 + qd * 4;
      *(float4*)(out + addr) = *(float4*)&acc[i][j];
    }
}

extern "C" void kernel_launch(void* const* d_in, const int* in_sizes, int n_in,
                              void* d_out, int out_size, void* d_ws, size_t ws_size,
                              hipStream_t stream) {
  const float* x  = (const float*)d_in[0];
  const float* Wv = (const float*)d_in[1];
  const float* bv = (const float*)d_in[2];
  const float* Wk = (const float*)d_in[3];
  const float* bk = (const float*)d_in[4];
  const float* Wq = (const float*)d_in[5];
  const float* bq = (const float*)d_in[6];
  const float* Wa = (const float*)d_in[7];
  const float* ba = (const float*)d_in[8];
  float* out = (float*)d_out;
  float* ws = (float*)d_ws;

  // float-unit offsets; total 20,168,704 fl = 80.7 MB
  float*  a_buf = ws;                          // 2,097,152 fl
  __bf16* qb    = (__bf16*)(ws + 2097152);     // 2,097,152 bf
  __bf16* kbs   = (__bf16*)(ws + 3145728);     // 2,097,152 bf
  __bf16* kt    = (__bf16*)(ws + 4194304);     // 2,097,152 bf
  __bf16* vt    = (__bf16*)(ws + 5242880);     // 8,388,608 bf
  __bf16* k_raw = (__bf16*)(ws + 9437184);     // 2,097,152 bf
  __bf16* q_raw = (__bf16*)(ws + 10485760);    // 2,097,152 bf
  __bf16* xb    = (__bf16*)(ws + 11534336);    // 8,388,608 bf
  __bf16* Wcat  = (__bf16*)(ws + 15728640);    // 458,752 bf
  __bf16* Gt    = xb;                          // overlay: xb dead after proj
  __bf16* St    = (__bf16*)(ws + 15958016);    // 8,388,608 bf
  float*  cpend = ws + 20152320;               // 16,384 fl

  conv_bf16<<<4096, 256, 0, stream>>>(x, xb);
  conv_w<<<224, 256, 0, stream>>>(Wv, Wk, Wq, Wa, Wcat);
  proj_mfma<<<dim3(128, 7), 256, 0, stream>>>(xb, Wcat, bv, bk, bq, ba,
                                              vt, k_raw, q_raw, a_buf);
  scan_cp<<<256, 64, 0, stream>>>(a_buf, k_raw, q_raw, kbs, qb, kt, cpend);
  gmm<<<512, 256, 0, stream>>>(vt, kt, cpend, Gt);
  scan_state<<<512, 256, 0, stream>>>(Gt, cpend, St);
  ymm<<<512, 256, 0, stream>>>(qb, kbs, vt, St, out);
}

// Round 3
// 185.628 us; speedup vs baseline: 1.1023x; 1.1023x over previous
//
#include <hip/hip_runtime.h>

// GLA forward, chunked. T=2048, B=8, IN=512, DV=512, NK=128, CHUNK=128, NCH=16.
// Round 7: identical to Round 6 (container infra failure ate the bench).
// scan_cp = SEGMENTED scan (8 segments x 16 steps per (c,b,n) chain, LDS
// prefix exchange). 2048 waves (2/SIMD), chain length 16 (was 128).
// proj swizzle + scan_state vec kept from R5.
//
// Layouts (cb = c*8+b, r = t_glob*8+b):
//   a_buf  fp32 [r][128]
//   k_raw/q_raw bf16 [r][128]
//   qb/kbs bf16 [r][128]          (q~ = q*cp, k~ = k/(cp+eps))
//   kt     bf16 [cb*128 + n][s]   (k~ transposed)
//   vt     bf16 [cb*512 + d][s]
//   Gt     bf16 [cb*512 + d][n]   (scan input, overlays xb)
//   St     bf16 [cb*512 + d][n]   (S_prev per chunk)

#define EPSV 1e-8f

typedef __bf16 bf16x8 __attribute__((ext_vector_type(8)));
typedef __bf16 bf16x4 __attribute__((ext_vector_type(4)));
typedef float f32x4 __attribute__((ext_vector_type(4)));

__device__ __forceinline__ void async_copy16(const void* g, void* l) {
  __builtin_amdgcn_global_load_lds(
      (const __attribute__((address_space(1))) void*)g,
      (__attribute__((address_space(3))) void*)l, 16, 0, 0);
}

// ---- fp32 -> bf16 conversion (8 elems/thread) ----
__global__ __launch_bounds__(256) void conv_bf16(const float* __restrict__ src,
                                                 __bf16* __restrict__ dst) {
  long i = ((long)blockIdx.x * 256 + threadIdx.x) * 8;
  float4 f0 = *(const float4*)(src + i);
  float4 f1 = *(const float4*)(src + i + 4);
  bf16x8 h;
  h[0] = (__bf16)f0.x; h[1] = (__bf16)f0.y; h[2] = (__bf16)f0.z; h[3] = (__bf16)f0.w;
  h[4] = (__bf16)f1.x; h[5] = (__bf16)f1.y; h[6] = (__bf16)f1.z; h[7] = (__bf16)f1.w;
  *(bf16x8*)(dst + i) = h;
}

// ---- concat Wv|Wk|Wq|Wa into bf16 [896][512] ----
__global__ __launch_bounds__(256) void conv_w(const float* __restrict__ Wv,
                                              const float* __restrict__ Wk,
                                              const float* __restrict__ Wq,
                                              const float* __restrict__ Wa,
                                              __bf16* __restrict__ dst) {
  long i = ((long)blockIdx.x * 256 + threadIdx.x) * 8;
  int row = (int)(i >> 9);
  int col = (int)(i & 511);
  const float* src;
  if (row < 512)      src = Wv + (long)row * 512 + col;
  else if (row < 640) src = Wk + (long)(row - 512) * 512 + col;
  else if (row < 768) src = Wq + (long)(row - 640) * 512 + col;
  else                src = Wa + (long)(row - 768) * 512 + col;
  float4 f0 = *(const float4*)(src);
  float4 f1 = *(const float4*)(src + 4);
  bf16x8 h;
  h[0] = (__bf16)f0.x; h[1] = (__bf16)f0.y; h[2] = (__bf16)f0.z; h[3] = (__bf16)f0.w;
  h[4] = (__bf16)f1.x; h[5] = (__bf16)f1.y; h[6] = (__bf16)f1.z; h[7] = (__bf16)f1.w;
  *(bf16x8*)(dst + i) = h;
}

// ---- K1: projection GEMM, bf16 MFMA. grid (128 Mtiles, 7 Ntiles) ----
// nt 0..3 -> vt (bf16, LDS-transposed); 4 -> k_raw; 5 -> q_raw; 6 -> alpha fp32.
// LDS tiles are [128 rows][4 slots of 16B] with slot ^= (row>>1)&3 swizzle.
// global_load_lds writes linearly (row, phys-slot lc); the SOURCE column-group
// is pre-permuted (lc ^ (lr>>1)&3) so a matching XOR on the ds_read slot
// recovers logical data and spreads 8 consecutive rows across 8 distinct
// 4-bank groups (2-way residual aliasing = free).
__global__ __launch_bounds__(256) void proj_mfma(
    const __bf16* __restrict__ xb, const __bf16* __restrict__ wcat,
    const float* __restrict__ bv, const float* __restrict__ bk,
    const float* __restrict__ bq, const float* __restrict__ ba,
    __bf16* __restrict__ vt, __bf16* __restrict__ kout,
    __bf16* __restrict__ qout, float* __restrict__ aout) {
  // 34816 B: staging (16 KB) first, transpose buffer reuses whole block
  __shared__ __attribute__((aligned(16))) char smem[128 * 136 * 2];
  __bf16* a_sm = (__bf16*)smem;
  __bf16* b_sm = a_sm + 128 * 32;
  __bf16* tr   = (__bf16*)smem;      // reused after K-loop (post-barrier)

  int tid = threadIdx.x;
  int lane = tid & 63, wave = tid >> 6;
  int mt = blockIdx.x, nt = blockIdx.y;
  int wr = wave >> 1, wcol = wave & 1;

  const __bf16* xtile = xb + (long)mt * 128 * 512;
  const __bf16* wtile = wcat + (long)nt * 128 * 512;

  f32x4 acc[4][4] = {};
  int lr = lane >> 2, lc = lane & 3;
  int l15 = lane & 15, qd = lane >> 4;
  // source-side swizzle: physical slot lc holds logical col-group lc^((lr>>1)&3)
  int slsrc = (lc ^ ((lr >> 1) & 3)) * 8;
  // read-side swizzle: logical slot qd lives at physical slot qd^((l15>>1)&3)
  int frd = (l15 >> 1) & 3;

  for (int k0 = 0; k0 < 512; k0 += 32) {
#pragma unroll
    for (int h = 0; h < 2; ++h) {
      int q = wave * 2 + h;
      int row = q * 16 + lr;
      async_copy16(xtile + (long)row * 512 + k0 + slsrc, &a_sm[q * 512]);
      async_copy16(wtile + (long)row * 512 + k0 + slsrc, &b_sm[q * 512]);
    }
    __syncthreads();
    bf16x8 af[4], bfr[4];
#pragma unroll
    for (int t = 0; t < 4; ++t) {
      af[t]  = *(const bf16x8*)&a_sm[(wr * 64 + t * 16 + l15) * 32 + (qd ^ frd) * 8];
      bfr[t] = *(const bf16x8*)&b_sm[(wcol * 64 + t * 16 + l15) * 32 + (qd ^ frd) * 8];
    }
#pragma unroll
    for (int i = 0; i < 4; ++i)
#pragma unroll
      for (int j = 0; j < 4; ++j)
        acc[i][j] = __builtin_amdgcn_mfma_f32_16x16x32_bf16(af[i], bfr[j], acc[i][j], 0, 0, 0);
    __syncthreads();
  }

  if (nt < 4) {
    // v path: bias, cast bf16, transpose in LDS, write vt coalesced-ish.
    // tr layout: [d(128)][b*16 + t_l] pitch 136.
    const float* bias = bv + nt * 128;
#pragma unroll
    for (int i = 0; i < 4; ++i)
#pragma unroll
      for (int j = 0; j < 4; ++j) {
        int col = wcol * 64 + j * 16 + l15;
        float bz = bias[col];
#pragma unroll
        for (int r = 0; r < 4; ++r) {
          int row = wr * 64 + i * 16 + qd * 4 + r;   // row = t_l*8 + b
          tr[col * 136 + (row & 7) * 16 + (row >> 3)] = (__bf16)(acc[i][j][r] + bz);
        }
      }
    __syncthreads();
    int cbase = (mt >> 3) * 8;        // chunk c * 8
    int s0 = (mt & 7) * 16;           // s offset within chunk
#pragma unroll
    for (int it = 0; it < 4; ++it) {
      int p = it * 256 + tid;         // 1024 (d,b) pairs
      int d = p & 127, b = p >> 7;
      bf16x8 u0 = *(const bf16x8*)&tr[d * 136 + b * 16];
      bf16x8 u1 = *(const bf16x8*)&tr[d * 136 + b * 16 + 8];
      __bf16* dst = vt + ((long)(cbase + b) * 512 + nt * 128 + d) * 128 + s0;
      *(bf16x8*)dst = u0;
      *(bf16x8*)(dst + 8) = u1;
    }
    return;
  }

  const float* bias; bool sig = false;
  __bf16* dstb = nullptr; float* dstf = nullptr;
  if (nt == 4)      { bias = bk; dstb = kout; }
  else if (nt == 5) { bias = bq; dstb = qout; }
  else              { bias = ba; dstf = aout; sig = true; }

#pragma unroll
  for (int i = 0; i < 4; ++i)
#pragma unroll
    for (int j = 0; j < 4; ++j) {
      int col = wcol * 64 + j * 16 + l15;
      float bz = bias[col];
#pragma unroll
      for (int r = 0; r < 4; ++r) {
        int row = wr * 64 + i * 16 + qd * 4 + r;
        float z = acc[i][j][r] + bz;
        long addr = ((long)mt * 128 + row) * 128 + col;
        if (sig) dstf[addr] = 1.f / (1.f + __expf(-z));
        else     dstb[addr] = (__bf16)z;
      }
    }
}

// ---- scan_cp: SEGMENTED cumprod scan ----
// Grid 256 blocks x 512 threads. Block = (c, b, nh): 64 n-values x 8 segments
// of 16 t-steps. Pass 1: per-thread segment product of max(a,eps) (a kept in
// 16 VGPRs). LDS prefix exchange (seg is wave-uniform -> uniform branch).
// Pass 2: sweep the 16 steps with prefix, emit kbs/qb/kt/cpend as before.
// 2048 waves total (2/SIMD across all CUs), chain length 16 (was 128).
__global__ __launch_bounds__(512) void scan_cp(const float* __restrict__ a,
                                               const __bf16* __restrict__ k,
                                               const __bf16* __restrict__ q,
                                               __bf16* __restrict__ kbs,
                                               __bf16* __restrict__ qb,
                                               __bf16* __restrict__ kt,
                                               float* __restrict__ cpend) {
  __shared__ float segprod[8][64];
  int tid = threadIdx.x;
  int nl = tid & 63;          // n within half (lane id -> coalesced)
  int seg = tid >> 6;         // 0..7, wave-uniform
  int bid = blockIdx.x;       // (c*8 + b)*2 + nh
  int nh = bid & 1;
  int b = (bid >> 1) & 7;
  int c = bid >> 4;
  int n = nh * 64 + nl;
  long base = ((long)c * 1024 + b) * 128 + n;  // element offset at t=0
  int t0 = seg * 16;

  float av[16];
  float p = 1.f;
#pragma unroll
  for (int i = 0; i < 16; ++i) {
    float v = fmaxf(a[base + (long)(t0 + i) * 1024], EPSV);
    av[i] = v;
    p *= v;
  }
  segprod[seg][nl] = p;
  __syncthreads();

  float prefix = 1.f;
#pragma unroll
  for (int s = 0; s < 7; ++s)
    if (s < seg) prefix *= segprod[s][nl];   // seg wave-uniform: no divergence
  if (seg == 7) cpend[(c * 8 + b) * 128 + n] = prefix * p;

  float cp = prefix;
  __bf16 ktbuf[16];
#pragma unroll
  for (int i = 0; i < 16; ++i) {
    long off = base + (long)(t0 + i) * 1024;
    cp *= av[i];
    float kk = (float)k[off] / (cp + EPSV);
    float qq = (float)q[off] * cp;
    __bf16 kh = (__bf16)kk;
    kbs[off] = kh;
    qb[off] = (__bf16)qq;
    ktbuf[i] = kh;
  }
  __bf16* dst = kt + ((long)((c * 8 + b) * 128 + n)) * 128 + t0;
#pragma unroll
  for (int i = 0; i < 2; ++i) {
    bf16x8 h;
#pragma unroll
    for (int j = 0; j < 8; ++j) h[j] = ktbuf[i * 8 + j];
    *(bf16x8*)(dst + i * 8) = h;
  }
}

// ---- gmm: Gt[d,n] = cpend[n] * sum_s vt[d,s]*kt[n,s].  grid 512 = cb*4+dt ----
__global__ __launch_bounds__(256) void gmm(const __bf16* __restrict__ vt,
                                           const __bf16* __restrict__ kt,
                                           const float* __restrict__ cpend,
                                           __bf16* __restrict__ Gt) {
  int tid = threadIdx.x, lane = tid & 63, wave = tid >> 6;
  int wr = wave >> 1, wc = wave & 1;
  int l15 = lane & 15, qd = lane >> 4;
  int cb = blockIdx.x >> 2, dt = blockIdx.x & 3;
  const __bf16* vbase = vt + ((long)cb * 512 + dt * 128) * 128;
  const __bf16* kbase = kt + (long)cb * 16384;
  f32x4 acc[4][4] = {};
#pragma unroll
  for (int kk = 0; kk < 4; ++kk) {
    int k0 = kk * 32;
    bf16x8 af[4], bfr[4];
#pragma unroll
    for (int i = 0; i < 4; ++i)
      af[i] = *(const bf16x8*)(vbase + (long)(wr * 64 + i * 16 + l15) * 128 + k0 + qd * 8);
#pragma unroll
    for (int j = 0; j < 4; ++j)
      bfr[j] = *(const bf16x8*)(kbase + (long)(wc * 64 + j * 16 + l15) * 128 + k0 + qd * 8);
#pragma unroll
    for (int i = 0; i < 4; ++i)
#pragma unroll
      for (int j = 0; j < 4; ++j)
        acc[i][j] = __builtin_amdgcn_mfma_f32_16x16x32_bf16(af[i], bfr[j], acc[i][j], 0, 0, 0);
  }
  float ce[4];
#pragma unroll
  for (int j = 0; j < 4; ++j) ce[j] = cpend[cb * 128 + wc * 64 + j * 16 + l15];
#pragma unroll
  for (int i = 0; i < 4; ++i)
#pragma unroll
    for (int j = 0; j < 4; ++j) {
      int col = wc * 64 + j * 16 + l15;
#pragma unroll
      for (int r = 0; r < 4; ++r) {
        int row = wr * 64 + i * 16 + qd * 4 + r;
        Gt[((long)cb * 512 + dt * 128 + row) * 128 + col] = (__bf16)(acc[i][j][r] * ce[j]);
      }
    }
}

// ---- scan_state: fp32 scan over chunks on Gt(bf16); emits St bf16 ----
// vectorized x4: 8B loads/stores per lane (was scalar 2B).
__global__ __launch_bounds__(256) void scan_state(const __bf16* __restrict__ Gt,
                                                  const float* __restrict__ cpend,
                                                  __bf16* __restrict__ St) {
  long e = ((long)blockIdx.x * 256 + threadIdx.x) * 4;  // 524288 = 8b*512d*128n
  int n0 = (int)(e & 127);
  int b = (int)(e >> 16);
  float4 S = {0.f, 0.f, 0.f, 0.f};
#pragma unroll
  for (int c = 0; c < 16; ++c) {
    long idx = (long)c * 524288 + e;
    bf16x4 g = *(const bf16x4*)(Gt + idx);
    bf16x4 sv;
    sv[0] = (__bf16)S.x; sv[1] = (__bf16)S.y;
    sv[2] = (__bf16)S.z; sv[3] = (__bf16)S.w;
    *(bf16x4*)(St + idx) = sv;
    const float4 cp = *(const float4*)(cpend + (c * 8 + b) * 128 + n0);
    S.x = (float)g[0] + S.x * cp.x;
    S.y = (float)g[1] + S.y * cp.y;
    S.z = (float)g[2] + S.z * cp.z;
    S.w = (float)g[3] + S.w * cp.w;
  }
}

// ---- ymm: y^T[d,t] = sum_s vt[d,s]*A[t,s] + sum_n St[d,n]*qb[t,n] ----
__global__ __launch_bounds__(256) void ymm(const __bf16* __restrict__ qb,
                                           const __bf16* __restrict__ kbs,
                                           const __bf16* __restrict__ vt,
                                           const __bf16* __restrict__ St,
                                           float* __restrict__ out) {
  __shared__ __bf16 A_lds[128 * 136];
  int tid = threadIdx.x, lane = tid & 63, wave = tid >> 6;
  int wr = wave >> 1, wc = wave & 1;
  int l15 = lane & 15, qd = lane >> 4;
  int cb = blockIdx.x >> 2, dt = blockIdx.x & 3;
  int c = cb >> 3, b = cb & 7;
  const __bf16* qbase = qb + ((long)c * 1024 + b) * 128;
  const __bf16* kbase = kbs + ((long)c * 1024 + b) * 128;

  {
    f32x4 accA[4][4] = {};
#pragma unroll
    for (int kk = 0; kk < 4; ++kk) {
      int k0 = kk * 32;
      bf16x8 af[4], bfr[4];
#pragma unroll
      for (int i = 0; i < 4; ++i)
        af[i] = *(const bf16x8*)(qbase + (long)(wr * 64 + i * 16 + l15) * 1024 + k0 + qd * 8);
#pragma unroll
      for (int j = 0; j < 4; ++j)
        bfr[j] = *(const bf16x8*)(kbase + (long)(wc * 64 + j * 16 + l15) * 1024 + k0 + qd * 8);
#pragma unroll
      for (int i = 0; i < 4; ++i)
#pragma unroll
        for (int j = 0; j < 4; ++j)
          accA[i][j] = __builtin_amdgcn_mfma_f32_16x16x32_bf16(af[i], bfr[j], accA[i][j], 0, 0, 0);
    }
#pragma unroll
    for (int i = 0; i < 4; ++i)
#pragma unroll
      for (int j = 0; j < 4; ++j) {
        int s = wc * 64 + j * 16 + l15;
#pragma unroll
        for (int r = 0; r < 4; ++r) {
          int t = wr * 64 + i * 16 + qd * 4 + r;
          A_lds[t * 136 + s] = (s <= t) ? (__bf16)accA[i][j][r] : (__bf16)0.f;
        }
      }
  }
  __syncthreads();

  f32x4 acc[4][4] = {};
  const __bf16* vbase = vt + ((long)cb * 512 + dt * 128) * 128;
  const __bf16* sbase = St + ((long)cb * 512 + dt * 128) * 128;
#pragma unroll
  for (int kk = 0; kk < 4; ++kk) {
    int k0 = kk * 32;
    bf16x8 af[4], bfr[4];
#pragma unroll
    for (int i = 0; i < 4; ++i)
      af[i] = *(const bf16x8*)(vbase + (long)(wr * 64 + i * 16 + l15) * 128 + k0 + qd * 8);
#pragma unroll
    for (int j = 0; j < 4; ++j)
      bfr[j] = *(const bf16x8*)&A_lds[(wc * 64 + j * 16 + l15) * 136 + k0 + qd * 8];
#pragma unroll
    for (int i = 0; i < 4; ++i)
#pragma unroll
      for (int j = 0; j < 4; ++j)
        acc[i][j] = __builtin_amdgcn_mfma_f32_16x16x32_bf16(af[i], bfr[j], acc[i][j], 0, 0, 0);
  }
#pragma unroll
  for (int kk = 0; kk < 4; ++kk) {
    int k0 = kk * 32;
    bf16x8 af[4], bfr[4];
#pragma unroll
    for (int i = 0; i < 4; ++i)
      af[i] = *(const bf16x8*)(sbase + (long)(wr * 64 + i * 16 + l15) * 128 + k0 + qd * 8);
#pragma unroll
    for (int j = 0; j < 4; ++j)
      bfr[j] = *(const bf16x8*)(qbase + (long)(wc * 64 + j * 16 + l15) * 1024 + k0 + qd * 8);
#pragma unroll
    for (int i = 0; i < 4; ++i)
#pragma unroll
      for (int j = 0; j < 4; ++j)
        acc[i][j] = __builtin_amdgcn_mfma_f32_16x16x32_bf16(af[i], bfr[j], acc[i][j], 0, 0, 0);
  }

#pragma unroll
  for (int i = 0; i < 4; ++i)
#pragma unroll
    for (int j = 0; j < 4; ++j) {
      int colt = wc * 64 + j * 16 + l15;
      long addr = ((long)(c * 128 + colt) * 8 + b) * 512 + dt * 128 + wr * 64 + i * 16 + qd * 4;
      *(float4*)(out + addr) = *(float4*)&acc[i][j];
    }
}

extern "C" void kernel_launch(void* const* d_in, const int* in_sizes, int n_in,
                              void* d_out, int out_size, void* d_ws, size_t ws_size,
                              hipStream_t stream) {
  const float* x  = (const float*)d_in[0];
  const float* Wv = (const float*)d_in[1];
  const float* bv = (const float*)d_in[2];
  const float* Wk = (const float*)d_in[3];
  const float* bk = (const float*)d_in[4];
  const float* Wq = (const float*)d_in[5];
  const float* bq = (const float*)d_in[6];
  const float* Wa = (const float*)d_in[7];
  const float* ba = (const float*)d_in[8];
  float* out = (float*)d_out;
  float* ws = (float*)d_ws;

  // float-unit offsets; total 20,168,704 fl = 80.7 MB
  float*  a_buf = ws;                          // 2,097,152 fl
  __bf16* qb    = (__bf16*)(ws + 2097152);     // 2,097,152 bf
  __bf16* kbs   = (__bf16*)(ws + 3145728);     // 2,097,152 bf
  __bf16* kt    = (__bf16*)(ws + 4194304);     // 2,097,152 bf
  __bf16* vt    = (__bf16*)(ws + 5242880);     // 8,388,608 bf
  __bf16* k_raw = (__bf16*)(ws + 9437184);     // 2,097,152 bf
  __bf16* q_raw = (__bf16*)(ws + 10485760);    // 2,097,152 bf
  __bf16* xb    = (__bf16*)(ws + 11534336);    // 8,388,608 bf
  __bf16* Wcat  = (__bf16*)(ws + 15728640);    // 458,752 bf
  __bf16* Gt    = xb;                          // overlay: xb dead after proj
  __bf16* St    = (__bf16*)(ws + 15958016);    // 8,388,608 bf
  float*  cpend = ws + 20152320;               // 16,384 fl

  conv_bf16<<<4096, 256, 0, stream>>>(x, xb);
  conv_w<<<224, 256, 0, stream>>>(Wv, Wk, Wq, Wa, Wcat);
  proj_mfma<<<dim3(128, 7), 256, 0, stream>>>(xb, Wcat, bv, bk, bq, ba,
                                              vt, k_raw, q_raw, a_buf);
  scan_cp<<<256, 512, 0, stream>>>(a_buf, k_raw, q_raw, kbs, qb, kt, cpend);
  gmm<<<512, 256, 0, stream>>>(vt, kt, cpend, Gt);
  scan_state<<<512, 256, 0, stream>>>(Gt, cpend, St);
  ymm<<<512, 256, 0, stream>>>(qb, kbs, vt, St, out);
}

// Round 5
// 183.184 us; speedup vs baseline: 1.1170x; 1.0133x over previous
//
#include <hip/hip_runtime.h>

// GLA forward, chunked. T=2048, B=8, IN=512, DV=512, NK=128, CHUNK=128, NCH=16.
// Round 9: R8's dbuf+raw-barrier proj RACED (failed correctness). Revert to
// the PROVEN single-buffer __syncthreads structure (R7) but with BK=64:
// 8 K-iterations instead of 16 -> half the vmcnt(0) barrier drains, 32 MFMA
// per barrier. Swizzle re-derived for 8-slot rows: phys slot = logical ^
// (row&7), source pre-permuted (lc8^lr8). scan_cp segmented (R6), scan_state
// vec x4 (R5) kept.
//
// Layouts (cb = c*8+b, r = t_glob*8+b):
//   a_buf  fp32 [r][128]
//   k_raw/q_raw bf16 [r][128]
//   qb/kbs bf16 [r][128]          (q~ = q*cp, k~ = k/(cp+eps))
//   kt     bf16 [cb*128 + n][s]   (k~ transposed)
//   vt     bf16 [cb*512 + d][s]
//   Gt     bf16 [cb*512 + d][n]   (scan input, overlays xb)
//   St     bf16 [cb*512 + d][n]   (S_prev per chunk)

#define EPSV 1e-8f

typedef __bf16 bf16x8 __attribute__((ext_vector_type(8)));
typedef __bf16 bf16x4 __attribute__((ext_vector_type(4)));
typedef float f32x4 __attribute__((ext_vector_type(4)));

__device__ __forceinline__ void async_copy16(const void* g, void* l) {
  __builtin_amdgcn_global_load_lds(
      (const __attribute__((address_space(1))) void*)g,
      (__attribute__((address_space(3))) void*)l, 16, 0, 0);
}

// ---- fp32 -> bf16 conversion (8 elems/thread) ----
__global__ __launch_bounds__(256) void conv_bf16(const float* __restrict__ src,
                                                 __bf16* __restrict__ dst) {
  long i = ((long)blockIdx.x * 256 + threadIdx.x) * 8;
  float4 f0 = *(const float4*)(src + i);
  float4 f1 = *(const float4*)(src + i + 4);
  bf16x8 h;
  h[0] = (__bf16)f0.x; h[1] = (__bf16)f0.y; h[2] = (__bf16)f0.z; h[3] = (__bf16)f0.w;
  h[4] = (__bf16)f1.x; h[5] = (__bf16)f1.y; h[6] = (__bf16)f1.z; h[7] = (__bf16)f1.w;
  *(bf16x8*)(dst + i) = h;
}

// ---- concat Wv|Wk|Wq|Wa into bf16 [896][512] ----
__global__ __launch_bounds__(256) void conv_w(const float* __restrict__ Wv,
                                              const float* __restrict__ Wk,
                                              const float* __restrict__ Wq,
                                              const float* __restrict__ Wa,
                                              __bf16* __restrict__ dst) {
  long i = ((long)blockIdx.x * 256 + threadIdx.x) * 8;
  int row = (int)(i >> 9);
  int col = (int)(i & 511);
  const float* src;
  if (row < 512)      src = Wv + (long)row * 512 + col;
  else if (row < 640) src = Wk + (long)(row - 512) * 512 + col;
  else if (row < 768) src = Wq + (long)(row - 640) * 512 + col;
  else                src = Wa + (long)(row - 768) * 512 + col;
  float4 f0 = *(const float4*)(src);
  float4 f1 = *(const float4*)(src + 4);
  bf16x8 h;
  h[0] = (__bf16)f0.x; h[1] = (__bf16)f0.y; h[2] = (__bf16)f0.z; h[3] = (__bf16)f0.w;
  h[4] = (__bf16)f1.x; h[5] = (__bf16)f1.y; h[6] = (__bf16)f1.z; h[7] = (__bf16)f1.w;
  *(bf16x8*)(dst + i) = h;
}

// ---- K1: projection GEMM, bf16 MFMA. grid (128 Mtiles, 7 Ntiles) ----
// nt 0..3 -> vt (bf16, LDS-transposed); 4 -> k_raw; 5 -> q_raw; 6 -> alpha fp32.
// BK=64: LDS tiles [128 rows][8 slots of 16B] (128B pitch). Swizzle: phys
// slot = logical ^ (row&7); global_load_lds writes linearly, so the SOURCE
// column-group is pre-permuted per lane (lc8 ^ lr8) and the matching XOR is
// applied on ds_read. 8 K-iterations, 32 MFMA per __syncthreads pair.
__global__ __launch_bounds__(256) void proj_mfma(
    const __bf16* __restrict__ xb, const __bf16* __restrict__ wcat,
    const float* __restrict__ bv, const float* __restrict__ bk,
    const float* __restrict__ bq, const float* __restrict__ ba,
    __bf16* __restrict__ vt, __bf16* __restrict__ kout,
    __bf16* __restrict__ qout, float* __restrict__ aout) {
  // 34816 B: staging (32 KB: A 16KB | B 16KB), tr overlays all (post-barrier)
  __shared__ __attribute__((aligned(16))) char smem[128 * 136 * 2];
  __bf16* a_sm = (__bf16*)smem;        // [128][64] elements
  __bf16* b_sm = a_sm + 128 * 64;
  __bf16* tr   = (__bf16*)smem;        // reused after K-loop (post-barrier)

  int tid = threadIdx.x;
  int lane = tid & 63, wave = tid >> 6;
  int mt = blockIdx.x, nt = blockIdx.y;
  int wr = wave >> 1, wcol = wave & 1;

  const __bf16* xtile = xb + (long)mt * 128 * 512;
  const __bf16* wtile = wcat + (long)nt * 128 * 512;

  f32x4 acc[4][4] = {};
  int lr8 = lane >> 3, lc8 = lane & 7;
  int l15 = lane & 15, qd = lane >> 4;
  // source-side swizzle: phys slot lc8 at row (..*8+lr8) holds logical lc8^lr8
  int slsrc = (lc8 ^ lr8) * 8;
  // read-side swizzle: logical slot L at row r lives at phys L ^ (r&7) = L^(l15&7)
  int frd = l15 & 7;

  for (int k0 = 0; k0 < 512; k0 += 64) {
#pragma unroll
    for (int h = 0; h < 4; ++h) {
      int q = wave * 4 + h;            // 0..15 blocks of 8 rows
      int row = q * 8 + lr8;
      async_copy16(xtile + (long)row * 512 + k0 + slsrc, &a_sm[q * 512]);
      async_copy16(wtile + (long)row * 512 + k0 + slsrc, &b_sm[q * 512]);
    }
    __syncthreads();
#pragma unroll
    for (int kk = 0; kk < 2; ++kk) {
      bf16x8 af[4], bfr[4];
#pragma unroll
      for (int t = 0; t < 4; ++t) {
        int ra = wr * 64 + t * 16 + l15;
        int rb = wcol * 64 + t * 16 + l15;
        int slot = ((kk * 4 + qd) ^ frd) * 8;
        af[t]  = *(const bf16x8*)&a_sm[ra * 64 + slot];
        bfr[t] = *(const bf16x8*)&b_sm[rb * 64 + slot];
      }
#pragma unroll
      for (int i = 0; i < 4; ++i)
#pragma unroll
        for (int j = 0; j < 4; ++j)
          acc[i][j] = __builtin_amdgcn_mfma_f32_16x16x32_bf16(af[i], bfr[j], acc[i][j], 0, 0, 0);
    }
    __syncthreads();
  }

  if (nt < 4) {
    // v path: bias, cast bf16, transpose in LDS, write vt coalesced-ish.
    // tr layout: [d(128)][b*16 + t_l] pitch 136.
    const float* bias = bv + nt * 128;
#pragma unroll
    for (int i = 0; i < 4; ++i)
#pragma unroll
      for (int j = 0; j < 4; ++j) {
        int col = wcol * 64 + j * 16 + l15;
        float bz = bias[col];
#pragma unroll
        for (int r = 0; r < 4; ++r) {
          int row = wr * 64 + i * 16 + qd * 4 + r;   // row = t_l*8 + b
          tr[col * 136 + (row & 7) * 16 + (row >> 3)] = (__bf16)(acc[i][j][r] + bz);
        }
      }
    __syncthreads();
    int cbase = (mt >> 3) * 8;        // chunk c * 8
    int s0 = (mt & 7) * 16;           // s offset within chunk
#pragma unroll
    for (int it = 0; it < 4; ++it) {
      int p = it * 256 + tid;         // 1024 (d,b) pairs
      int d = p & 127, b = p >> 7;
      bf16x8 u0 = *(const bf16x8*)&tr[d * 136 + b * 16];
      bf16x8 u1 = *(const bf16x8*)&tr[d * 136 + b * 16 + 8];
      __bf16* dst = vt + ((long)(cbase + b) * 512 + nt * 128 + d) * 128 + s0;
      *(bf16x8*)dst = u0;
      *(bf16x8*)(dst + 8) = u1;
    }
    return;
  }

  const float* bias; bool sig = false;
  __bf16* dstb = nullptr; float* dstf = nullptr;
  if (nt == 4)      { bias = bk; dstb = kout; }
  else if (nt == 5) { bias = bq; dstb = qout; }
  else              { bias = ba; dstf = aout; sig = true; }

#pragma unroll
  for (int i = 0; i < 4; ++i)
#pragma unroll
    for (int j = 0; j < 4; ++j) {
      int col = wcol * 64 + j * 16 + l15;
      float bz = bias[col];
#pragma unroll
      for (int r = 0; r < 4; ++r) {
        int row = wr * 64 + i * 16 + qd * 4 + r;
        float z = acc[i][j][r] + bz;
        long addr = ((long)mt * 128 + row) * 128 + col;
        if (sig) dstf[addr] = 1.f / (1.f + __expf(-z));
        else     dstb[addr] = (__bf16)z;
      }
    }
}

// ---- scan_cp: SEGMENTED cumprod scan ----
// Grid 256 blocks x 512 threads. Block = (c, b, nh): 64 n-values x 8 segments
// of 16 t-steps. Pass 1: per-thread segment product of max(a,eps) (a kept in
// 16 VGPRs). LDS prefix exchange (seg is wave-uniform -> uniform branch).
// Pass 2: sweep the 16 steps with prefix, emit kbs/qb/kt/cpend as before.
__global__ __launch_bounds__(512) void scan_cp(const float* __restrict__ a,
                                               const __bf16* __restrict__ k,
                                               const __bf16* __restrict__ q,
                                               __bf16* __restrict__ kbs,
                                               __bf16* __restrict__ qb,
                                               __bf16* __restrict__ kt,
                                               float* __restrict__ cpend) {
  __shared__ float segprod[8][64];
  int tid = threadIdx.x;
  int nl = tid & 63;          // n within half (lane id -> coalesced)
  int seg = tid >> 6;         // 0..7, wave-uniform
  int bid = blockIdx.x;       // (c*8 + b)*2 + nh
  int nh = bid & 1;
  int b = (bid >> 1) & 7;
  int c = bid >> 4;
  int n = nh * 64 + nl;
  long base = ((long)c * 1024 + b) * 128 + n;  // element offset at t=0
  int t0 = seg * 16;

  float av[16];
  float p = 1.f;
#pragma unroll
  for (int i = 0; i < 16; ++i) {
    float v = fmaxf(a[base + (long)(t0 + i) * 1024], EPSV);
    av[i] = v;
    p *= v;
  }
  segprod[seg][nl] = p;
  __syncthreads();

  float prefix = 1.f;
#pragma unroll
  for (int s = 0; s < 7; ++s)
    if (s < seg) prefix *= segprod[s][nl];   // seg wave-uniform: no divergence
  if (seg == 7) cpend[(c * 8 + b) * 128 + n] = prefix * p;

  float cp = prefix;
  __bf16 ktbuf[16];
#pragma unroll
  for (int i = 0; i < 16; ++i) {
    long off = base + (long)(t0 + i) * 1024;
    cp *= av[i];
    float kk = (float)k[off] / (cp + EPSV);
    float qq = (float)q[off] * cp;
    __bf16 kh = (__bf16)kk;
    kbs[off] = kh;
    qb[off] = (__bf16)qq;
    ktbuf[i] = kh;
  }
  __bf16* dst = kt + ((long)((c * 8 + b) * 128 + n)) * 128 + t0;
#pragma unroll
  for (int i = 0; i < 2; ++i) {
    bf16x8 h;
#pragma unroll
    for (int j = 0; j < 8; ++j) h[j] = ktbuf[i * 8 + j];
    *(bf16x8*)(dst + i * 8) = h;
  }
}

// ---- gmm: Gt[d,n] = cpend[n] * sum_s vt[d,s]*kt[n,s].  grid 512 = cb*4+dt ----
__global__ __launch_bounds__(256) void gmm(const __bf16* __restrict__ vt,
                                           const __bf16* __restrict__ kt,
                                           const float* __restrict__ cpend,
                                           __bf16* __restrict__ Gt) {
  int tid = threadIdx.x, lane = tid & 63, wave = tid >> 6;
  int wr = wave >> 1, wc = wave & 1;
  int l15 = lane & 15, qd = lane >> 4;
  int cb = blockIdx.x >> 2, dt = blockIdx.x & 3;
  const __bf16* vbase = vt + ((long)cb * 512 + dt * 128) * 128;
  const __bf16* kbase = kt + (long)cb * 16384;
  f32x4 acc[4][4] = {};
#pragma unroll
  for (int kk = 0; kk < 4; ++kk) {
    int k0 = kk * 32;
    bf16x8 af[4], bfr[4];
#pragma unroll
    for (int i = 0; i < 4; ++i)
      af[i] = *(const bf16x8*)(vbase + (long)(wr * 64 + i * 16 + l15) * 128 + k0 + qd * 8);
#pragma unroll
    for (int j = 0; j < 4; ++j)
      bfr[j] = *(const bf16x8*)(kbase + (long)(wc * 64 + j * 16 + l15) * 128 + k0 + qd * 8);
#pragma unroll
    for (int i = 0; i < 4; ++i)
#pragma unroll
      for (int j = 0; j < 4; ++j)
        acc[i][j] = __builtin_amdgcn_mfma_f32_16x16x32_bf16(af[i], bfr[j], acc[i][j], 0, 0, 0);
  }
  float ce[4];
#pragma unroll
  for (int j = 0; j < 4; ++j) ce[j] = cpend[cb * 128 + wc * 64 + j * 16 + l15];
#pragma unroll
  for (int i = 0; i < 4; ++i)
#pragma unroll
    for (int j = 0; j < 4; ++j) {
      int col = wc * 64 + j * 16 + l15;
#pragma unroll
      for (int r = 0; r < 4; ++r) {
        int row = wr * 64 + i * 16 + qd * 4 + r;
        Gt[((long)cb * 512 + dt * 128 + row) * 128 + col] = (__bf16)(acc[i][j][r] * ce[j]);
      }
    }
}

// ---- scan_state: fp32 scan over chunks on Gt(bf16); emits St bf16 ----
// vectorized x4: 8B loads/stores per lane.
__global__ __launch_bounds__(256) void scan_state(const __bf16* __restrict__ Gt,
                                                  const float* __restrict__ cpend,
                                                  __bf16* __restrict__ St) {
  long e = ((long)blockIdx.x * 256 + threadIdx.x) * 4;  // 524288 = 8b*512d*128n
  int n0 = (int)(e & 127);
  int b = (int)(e >> 16);
  float4 S = {0.f, 0.f, 0.f, 0.f};
#pragma unroll
  for (int c = 0; c < 16; ++c) {
    long idx = (long)c * 524288 + e;
    bf16x4 g = *(const bf16x4*)(Gt + idx);
    bf16x4 sv;
    sv[0] = (__bf16)S.x; sv[1] = (__bf16)S.y;
    sv[2] = (__bf16)S.z; sv[3] = (__bf16)S.w;
    *(bf16x4*)(St + idx) = sv;
    const float4 cp = *(const float4*)(cpend + (c * 8 + b) * 128 + n0);
    S.x = (float)g[0] + S.x * cp.x;
    S.y = (float)g[1] + S.y * cp.y;
    S.z = (float)g[2] + S.z * cp.z;
    S.w = (float)g[3] + S.w * cp.w;
  }
}

// ---- ymm: y^T[d,t] = sum_s vt[d,s]*A[t,s] + sum_n St[d,n]*qb[t,n] ----
__global__ __launch_bounds__(256) void ymm(const __bf16* __restrict__ qb,
                                           const __bf16* __restrict__ kbs,
                                           const __bf16* __restrict__ vt,
                                           const __bf16* __restrict__ St,
                                           float* __restrict__ out) {
  __shared__ __bf16 A_lds[128 * 136];
  int tid = threadIdx.x, lane = tid & 63, wave = tid >> 6;
  int wr = wave >> 1, wc = wave & 1;
  int l15 = lane & 15, qd = lane >> 4;
  int cb = blockIdx.x >> 2, dt = blockIdx.x & 3;
  int c = cb >> 3, b = cb & 7;
  const __bf16* qbase = qb + ((long)c * 1024 + b) * 128;
  const __bf16* kbase = kbs + ((long)c * 1024 + b) * 128;

  {
    f32x4 accA[4][4] = {};
#pragma unroll
    for (int kk = 0; kk < 4; ++kk) {
      int k0 = kk * 32;
      bf16x8 af[4], bfr[4];
#pragma unroll
      for (int i = 0; i < 4; ++i)
        af[i] = *(const bf16x8*)(qbase + (long)(wr * 64 + i * 16 + l15) * 1024 + k0 + qd * 8);
#pragma unroll
      for (int j = 0; j < 4; ++j)
        bfr[j] = *(const bf16x8*)(kbase + (long)(wc * 64 + j * 16 + l15) * 1024 + k0 + qd * 8);
#pragma unroll
      for (int i = 0; i < 4; ++i)
#pragma unroll
        for (int j = 0; j < 4; ++j)
          accA[i][j] = __builtin_amdgcn_mfma_f32_16x16x32_bf16(af[i], bfr[j], accA[i][j], 0, 0, 0);
    }
#pragma unroll
    for (int i = 0; i < 4; ++i)
#pragma unroll
      for (int j = 0; j < 4; ++j) {
        int s = wc * 64 + j * 16 + l15;
#pragma unroll
        for (int r = 0; r < 4; ++r) {
          int t = wr * 64 + i * 16 + qd * 4 + r;
          A_lds[t * 136 + s] = (s <= t) ? (__bf16)accA[i][j][r] : (__bf16)0.f;
        }
      }
  }
  __syncthreads();

  f32x4 acc[4][4] = {};
  const __bf16* vbase = vt + ((long)cb * 512 + dt * 128) * 128;
  const __bf16* sbase = St + ((long)cb * 512 + dt * 128) * 128;
#pragma unroll
  for (int kk = 0; kk < 4; ++kk) {
    int k0 = kk * 32;
    bf16x8 af[4], bfr[4];
#pragma unroll
    for (int i = 0; i < 4; ++i)
      af[i] = *(const bf16x8*)(vbase + (long)(wr * 64 + i * 16 + l15) * 128 + k0 + qd * 8);
#pragma unroll
    for (int j = 0; j < 4; ++j)
      bfr[j] = *(const bf16x8*)&A_lds[(wc * 64 + j * 16 + l15) * 136 + k0 + qd * 8];
#pragma unroll
    for (int i = 0; i < 4; ++i)
#pragma unroll
      for (int j = 0; j < 4; ++j)
        acc[i][j] = __builtin_amdgcn_mfma_f32_16x16x32_bf16(af[i], bfr[j], acc[i][j], 0, 0, 0);
  }
#pragma unroll
  for (int kk = 0; kk < 4; ++kk) {
    int k0 = kk * 32;
    bf16x8 af[4], bfr[4];
#pragma unroll
    for (int i = 0; i < 4; ++i)
      af[i] = *(const bf16x8*)(sbase + (long)(wr * 64 + i * 16 + l15) * 128 + k0 + qd * 8);
#pragma unroll
    for (int j = 0; j < 4; ++j)
      bfr[j] = *(const bf16x8*)(qbase + (long)(wc * 64 + j * 16 + l15) * 1024 + k0 + qd * 8);
#pragma unroll
    for (int i = 0; i < 4; ++i)
#pragma unroll
      for (int j = 0; j < 4; ++j)
        acc[i][j] = __builtin_amdgcn_mfma_f32_16x16x32_bf16(af[i], bfr[j], acc[i][j], 0, 0, 0);
  }

#pragma unroll
  for (int i = 0; i < 4; ++i)
#pragma unroll
    for (int j = 0; j < 4; ++j) {
      int colt = wc * 64 + j * 16 + l15;
      long addr = ((long)(c * 128 + colt) * 8 + b) * 512 + dt * 128 + wr * 64 + i * 16 + qd * 4;
      *(float4*)(out + addr) = *(float4*)&acc[i][j];
    }
}

extern "C" void kernel_launch(void* const* d_in, const int* in_sizes, int n_in,
                              void* d_out, int out_size, void* d_ws, size_t ws_size,
                              hipStream_t stream) {
  const float* x  = (const float*)d_in[0];
  const float* Wv = (const float*)d_in[1];
  const float* bv = (const float*)d_in[2];
  const float* Wk = (const float*)d_in[3];
  const float* bk = (const float*)d_in[4];
  const float* Wq = (const float*)d_in[5];
  const float* bq = (const float*)d_in[6];
  const float* Wa = (const float*)d_in[7];
  const float* ba = (const float*)d_in[8];
  float* out = (float*)d_out;
  float* ws = (float*)d_ws;

  // float-unit offsets; total 20,168,704 fl = 80.7 MB
  float*  a_buf = ws;                          // 2,097,152 fl
  __bf16* qb    = (__bf16*)(ws + 2097152);     // 2,097,152 bf
  __bf16* kbs   = (__bf16*)(ws + 3145728);     // 2,097,152 bf
  __bf16* kt    = (__bf16*)(ws + 4194304);     // 2,097,152 bf
  __bf16* vt    = (__bf16*)(ws + 5242880);     // 8,388,608 bf
  __bf16* k_raw = (__bf16*)(ws + 9437184);     // 2,097,152 bf
  __bf16* q_raw = (__bf16*)(ws + 10485760);    // 2,097,152 bf
  __bf16* xb    = (__bf16*)(ws + 11534336);    // 8,388,608 bf
  __bf16* Wcat  = (__bf16*)(ws + 15728640);    // 458,752 bf
  __bf16* Gt    = xb;                          // overlay: xb dead after proj
  __bf16* St    = (__bf16*)(ws + 15958016);    // 8,388,608 bf
  float*  cpend = ws + 20152320;               // 16,384 fl

  conv_bf16<<<4096, 256, 0, stream>>>(x, xb);
  conv_w<<<224, 256, 0, stream>>>(Wv, Wk, Wq, Wa, Wcat);
  proj_mfma<<<dim3(128, 7), 256, 0, stream>>>(xb, Wcat, bv, bk, bq, ba,
                                              vt, k_raw, q_raw, a_buf);
  scan_cp<<<256, 512, 0, stream>>>(a_buf, k_raw, q_raw, kbs, qb, kt, cpend);
  gmm<<<512, 256, 0, stream>>>(vt, kt, cpend, Gt);
  scan_state<<<512, 256, 0, stream>>>(Gt, cpend, St);
  ymm<<<512, 256, 0, stream>>>(qb, kbs, vt, St, out);
}

// Round 6
// 178.408 us; speedup vs baseline: 1.1469x; 1.0268x over previous
//
#include <hip/hip_runtime.h>

// GLA forward, chunked. T=2048, B=8, IN=512, DV=512, NK=128, CHUNK=128, NCH=16.
// Round 10: gmm and ymm rewritten with LDS staging (global_load_lds 16B/lane,
// 16-slot XOR involution swizzle) replacing direct global gathers. ymm also
// hoists all three GEMM phases onto staged operands with sequential S2 reuse
// (kbs -> vt -> St) and computes from LDS only. Plain __syncthreads only.
// proj BK=64 (R9), scan_cp segmented (R6), scan_state vec x4 (R5) kept.
//
// Layouts (cb = c*8+b, r = t_glob*8+b):
//   a_buf  fp32 [r][128]
//   k_raw/q_raw bf16 [r][128]
//   qb/kbs bf16 [r][128]          (q~ = q*cp, k~ = k/(cp+eps))
//   kt     bf16 [cb*128 + n][s]   (k~ transposed)
//   vt     bf16 [cb*512 + d][s]
//   Gt     bf16 [cb*512 + d][n]   (scan input, overlays xb)
//   St     bf16 [cb*512 + d][n]   (S_prev per chunk)

#define EPSV 1e-8f

typedef __bf16 bf16x8 __attribute__((ext_vector_type(8)));
typedef __bf16 bf16x4 __attribute__((ext_vector_type(4)));
typedef float f32x4 __attribute__((ext_vector_type(4)));

__device__ __forceinline__ void async_copy16(const void* g, void* l) {
  __builtin_amdgcn_global_load_lds(
      (const __attribute__((address_space(1))) void*)g,
      (__attribute__((address_space(3))) void*)l, 16, 0, 0);
}

// ---- fp32 -> bf16 conversion (8 elems/thread) ----
__global__ __launch_bounds__(256) void conv_bf16(const float* __restrict__ src,
                                                 __bf16* __restrict__ dst) {
  long i = ((long)blockIdx.x * 256 + threadIdx.x) * 8;
  float4 f0 = *(const float4*)(src + i);
  float4 f1 = *(const float4*)(src + i + 4);
  bf16x8 h;
  h[0] = (__bf16)f0.x; h[1] = (__bf16)f0.y; h[2] = (__bf16)f0.z; h[3] = (__bf16)f0.w;
  h[4] = (__bf16)f1.x; h[5] = (__bf16)f1.y; h[6] = (__bf16)f1.z; h[7] = (__bf16)f1.w;
  *(bf16x8*)(dst + i) = h;
}

// ---- concat Wv|Wk|Wq|Wa into bf16 [896][512] ----
__global__ __launch_bounds__(256) void conv_w(const float* __restrict__ Wv,
                                              const float* __restrict__ Wk,
                                              const float* __restrict__ Wq,
                                              const float* __restrict__ Wa,
                                              __bf16* __restrict__ dst) {
  long i = ((long)blockIdx.x * 256 + threadIdx.x) * 8;
  int row = (int)(i >> 9);
  int col = (int)(i & 511);
  const float* src;
  if (row < 512)      src = Wv + (long)row * 512 + col;
  else if (row < 640) src = Wk + (long)(row - 512) * 512 + col;
  else if (row < 768) src = Wq + (long)(row - 640) * 512 + col;
  else                src = Wa + (long)(row - 768) * 512 + col;
  float4 f0 = *(const float4*)(src);
  float4 f1 = *(const float4*)(src + 4);
  bf16x8 h;
  h[0] = (__bf16)f0.x; h[1] = (__bf16)f0.y; h[2] = (__bf16)f0.z; h[3] = (__bf16)f0.w;
  h[4] = (__bf16)f1.x; h[5] = (__bf16)f1.y; h[6] = (__bf16)f1.z; h[7] = (__bf16)f1.w;
  *(bf16x8*)(dst + i) = h;
}

// ---- K1: projection GEMM, bf16 MFMA. grid (128 Mtiles, 7 Ntiles) ----
// nt 0..3 -> vt (bf16, LDS-transposed); 4 -> k_raw; 5 -> q_raw; 6 -> alpha fp32.
// BK=64: LDS tiles [128 rows][8 slots of 16B] (128B pitch), phys slot =
// logical ^ (row&7), source pre-permuted. 8 K-iterations.
__global__ __launch_bounds__(256) void proj_mfma(
    const __bf16* __restrict__ xb, const __bf16* __restrict__ wcat,
    const float* __restrict__ bv, const float* __restrict__ bk,
    const float* __restrict__ bq, const float* __restrict__ ba,
    __bf16* __restrict__ vt, __bf16* __restrict__ kout,
    __bf16* __restrict__ qout, float* __restrict__ aout) {
  __shared__ __attribute__((aligned(16))) char smem[128 * 136 * 2];
  __bf16* a_sm = (__bf16*)smem;        // [128][64]
  __bf16* b_sm = a_sm + 128 * 64;
  __bf16* tr   = (__bf16*)smem;        // reused after K-loop (post-barrier)

  int tid = threadIdx.x;
  int lane = tid & 63, wave = tid >> 6;
  int mt = blockIdx.x, nt = blockIdx.y;
  int wr = wave >> 1, wcol = wave & 1;

  const __bf16* xtile = xb + (long)mt * 128 * 512;
  const __bf16* wtile = wcat + (long)nt * 128 * 512;

  f32x4 acc[4][4] = {};
  int lr8 = lane >> 3, lc8 = lane & 7;
  int l15 = lane & 15, qd = lane >> 4;
  int slsrc = (lc8 ^ lr8) * 8;
  int frd = l15 & 7;

  for (int k0 = 0; k0 < 512; k0 += 64) {
#pragma unroll
    for (int h = 0; h < 4; ++h) {
      int q = wave * 4 + h;
      int row = q * 8 + lr8;
      async_copy16(xtile + (long)row * 512 + k0 + slsrc, &a_sm[q * 512]);
      async_copy16(wtile + (long)row * 512 + k0 + slsrc, &b_sm[q * 512]);
    }
    __syncthreads();
#pragma unroll
    for (int kk = 0; kk < 2; ++kk) {
      bf16x8 af[4], bfr[4];
#pragma unroll
      for (int t = 0; t < 4; ++t) {
        int ra = wr * 64 + t * 16 + l15;
        int rb = wcol * 64 + t * 16 + l15;
        int slot = ((kk * 4 + qd) ^ frd) * 8;
        af[t]  = *(const bf16x8*)&a_sm[ra * 64 + slot];
        bfr[t] = *(const bf16x8*)&b_sm[rb * 64 + slot];
      }
#pragma unroll
      for (int i = 0; i < 4; ++i)
#pragma unroll
        for (int j = 0; j < 4; ++j)
          acc[i][j] = __builtin_amdgcn_mfma_f32_16x16x32_bf16(af[i], bfr[j], acc[i][j], 0, 0, 0);
    }
    __syncthreads();
  }

  if (nt < 4) {
    const float* bias = bv + nt * 128;
#pragma unroll
    for (int i = 0; i < 4; ++i)
#pragma unroll
      for (int j = 0; j < 4; ++j) {
        int col = wcol * 64 + j * 16 + l15;
        float bz = bias[col];
#pragma unroll
        for (int r = 0; r < 4; ++r) {
          int row = wr * 64 + i * 16 + qd * 4 + r;   // row = t_l*8 + b
          tr[col * 136 + (row & 7) * 16 + (row >> 3)] = (__bf16)(acc[i][j][r] + bz);
        }
      }
    __syncthreads();
    int cbase = (mt >> 3) * 8;
    int s0 = (mt & 7) * 16;
#pragma unroll
    for (int it = 0; it < 4; ++it) {
      int p = it * 256 + tid;
      int d = p & 127, b = p >> 7;
      bf16x8 u0 = *(const bf16x8*)&tr[d * 136 + b * 16];
      bf16x8 u1 = *(const bf16x8*)&tr[d * 136 + b * 16 + 8];
      __bf16* dst = vt + ((long)(cbase + b) * 512 + nt * 128 + d) * 128 + s0;
      *(bf16x8*)dst = u0;
      *(bf16x8*)(dst + 8) = u1;
    }
    return;
  }

  const float* bias; bool sig = false;
  __bf16* dstb = nullptr; float* dstf = nullptr;
  if (nt == 4)      { bias = bk; dstb = kout; }
  else if (nt == 5) { bias = bq; dstb = qout; }
  else              { bias = ba; dstf = aout; sig = true; }

#pragma unroll
  for (int i = 0; i < 4; ++i)
#pragma unroll
    for (int j = 0; j < 4; ++j) {
      int col = wcol * 64 + j * 16 + l15;
      float bz = bias[col];
#pragma unroll
      for (int r = 0; r < 4; ++r) {
        int row = wr * 64 + i * 16 + qd * 4 + r;
        float z = acc[i][j][r] + bz;
        long addr = ((long)mt * 128 + row) * 128 + col;
        if (sig) dstf[addr] = 1.f / (1.f + __expf(-z));
        else     dstb[addr] = (__bf16)z;
      }
    }
}

// ---- scan_cp: SEGMENTED cumprod scan (R6) ----
__global__ __launch_bounds__(512) void scan_cp(const float* __restrict__ a,
                                               const __bf16* __restrict__ k,
                                               const __bf16* __restrict__ q,
                                               __bf16* __restrict__ kbs,
                                               __bf16* __restrict__ qb,
                                               __bf16* __restrict__ kt,
                                               float* __restrict__ cpend) {
  __shared__ float segprod[8][64];
  int tid = threadIdx.x;
  int nl = tid & 63;
  int seg = tid >> 6;
  int bid = blockIdx.x;
  int nh = bid & 1;
  int b = (bid >> 1) & 7;
  int c = bid >> 4;
  int n = nh * 64 + nl;
  long base = ((long)c * 1024 + b) * 128 + n;
  int t0 = seg * 16;

  float av[16];
  float p = 1.f;
#pragma unroll
  for (int i = 0; i < 16; ++i) {
    float v = fmaxf(a[base + (long)(t0 + i) * 1024], EPSV);
    av[i] = v;
    p *= v;
  }
  segprod[seg][nl] = p;
  __syncthreads();

  float prefix = 1.f;
#pragma unroll
  for (int s = 0; s < 7; ++s)
    if (s < seg) prefix *= segprod[s][nl];
  if (seg == 7) cpend[(c * 8 + b) * 128 + n] = prefix * p;

  float cp = prefix;
  __bf16 ktbuf[16];
#pragma unroll
  for (int i = 0; i < 16; ++i) {
    long off = base + (long)(t0 + i) * 1024;
    cp *= av[i];
    float kk = (float)k[off] / (cp + EPSV);
    float qq = (float)q[off] * cp;
    __bf16 kh = (__bf16)kk;
    kbs[off] = kh;
    qb[off] = (__bf16)qq;
    ktbuf[i] = kh;
  }
  __bf16* dst = kt + ((long)((c * 8 + b) * 128 + n)) * 128 + t0;
#pragma unroll
  for (int i = 0; i < 2; ++i) {
    bf16x8 h;
#pragma unroll
    for (int j = 0; j < 8; ++j) h[j] = ktbuf[i * 8 + j];
    *(bf16x8*)(dst + i * 8) = h;
  }
}

// ---- gmm: Gt[d,n] = cpend[n] * sum_s vt[d,s]*kt[n,s].  grid 512 = cb*4+dt ----
// LDS-staged: vt-slab + kt-slab (32 KB each, contiguous) via global_load_lds,
// 16-slot XOR involution (phys slot = logical ^ (row&15), source pre-permuted).
__global__ __launch_bounds__(256) void gmm(const __bf16* __restrict__ vt,
                                           const __bf16* __restrict__ kt,
                                           const float* __restrict__ cpend,
                                           __bf16* __restrict__ Gt) {
  __shared__ __attribute__((aligned(16))) __bf16 v_sm[128 * 128];
  __shared__ __attribute__((aligned(16))) __bf16 k_sm[128 * 128];
  int tid = threadIdx.x, lane = tid & 63, wave = tid >> 6;
  int wr = wave >> 1, wc = wave & 1;
  int l15 = lane & 15, qd = lane >> 4;
  int cb = blockIdx.x >> 2, dt = blockIdx.x & 3;
  const __bf16* vbase = vt + ((long)cb * 512 + dt * 128) * 128;
  const __bf16* kbase = kt + (long)cb * 16384;

  int rowoff = lane >> 4, sl = lane & 15;
#pragma unroll
  for (int it = 0; it < 8; ++it) {
    int rbase = it * 16 + wave * 4;
    int row = rbase + rowoff;
    int sg = (sl ^ (row & 15)) * 8;
    async_copy16(vbase + (long)row * 128 + sg, &v_sm[rbase * 128]);
    async_copy16(kbase + (long)row * 128 + sg, &k_sm[rbase * 128]);
  }
  __syncthreads();

  f32x4 acc[4][4] = {};
#pragma unroll
  for (int kk = 0; kk < 4; ++kk) {
    bf16x8 af[4], bfr[4];
#pragma unroll
    for (int i = 0; i < 4; ++i) {
      int ra = wr * 64 + i * 16 + l15;          // ra & 15 == l15
      af[i] = *(const bf16x8*)&v_sm[ra * 128 + (((kk * 4 + qd) ^ l15) & 15) * 8];
    }
#pragma unroll
    for (int j = 0; j < 4; ++j) {
      int rb = wc * 64 + j * 16 + l15;
      bfr[j] = *(const bf16x8*)&k_sm[rb * 128 + (((kk * 4 + qd) ^ l15) & 15) * 8];
    }
#pragma unroll
    for (int i = 0; i < 4; ++i)
#pragma unroll
      for (int j = 0; j < 4; ++j)
        acc[i][j] = __builtin_amdgcn_mfma_f32_16x16x32_bf16(af[i], bfr[j], acc[i][j], 0, 0, 0);
  }
  float ce[4];
#pragma unroll
  for (int j = 0; j < 4; ++j) ce[j] = cpend[cb * 128 + wc * 64 + j * 16 + l15];
#pragma unroll
  for (int i = 0; i < 4; ++i)
#pragma unroll
    for (int j = 0; j < 4; ++j) {
      int col = wc * 64 + j * 16 + l15;
#pragma unroll
      for (int r = 0; r < 4; ++r) {
        int row = wr * 64 + i * 16 + qd * 4 + r;
        Gt[((long)cb * 512 + dt * 128 + row) * 128 + col] = (__bf16)(acc[i][j][r] * ce[j]);
      }
    }
}

// ---- scan_state: fp32 scan over chunks on Gt(bf16); emits St bf16 ----
// vectorized x4: 8B loads/stores per lane.
__global__ __launch_bounds__(256) void scan_state(const __bf16* __restrict__ Gt,
                                                  const float* __restrict__ cpend,
                                                  __bf16* __restrict__ St) {
  long e = ((long)blockIdx.x * 256 + threadIdx.x) * 4;
  int n0 = (int)(e & 127);
  int b = (int)(e >> 16);
  float4 S = {0.f, 0.f, 0.f, 0.f};
#pragma unroll
  for (int c = 0; c < 16; ++c) {
    long idx = (long)c * 524288 + e;
    bf16x4 g = *(const bf16x4*)(Gt + idx);
    bf16x4 sv;
    sv[0] = (__bf16)S.x; sv[1] = (__bf16)S.y;
    sv[2] = (__bf16)S.z; sv[3] = (__bf16)S.w;
    *(bf16x4*)(St + idx) = sv;
    const float4 cp = *(const float4*)(cpend + (c * 8 + b) * 128 + n0);
    S.x = (float)g[0] + S.x * cp.x;
    S.y = (float)g[1] + S.y * cp.y;
    S.z = (float)g[2] + S.z * cp.z;
    S.w = (float)g[3] + S.w * cp.w;
  }
}

// ---- ymm: y^T[d,t] = sum_s vt[d,s]*A[t,s] + sum_n St[d,n]*qb[t,n] ----
// All-staged: S1=qb (P1 af, P3 bfr), S2=kbs -> vt -> St (sequential reuse),
// A_lds pitch-136 (unchanged). Plain __syncthreads between phases.
__global__ __launch_bounds__(256) void ymm(const __bf16* __restrict__ qb,
                                           const __bf16* __restrict__ kbs,
                                           const __bf16* __restrict__ vt,
                                           const __bf16* __restrict__ St,
                                           float* __restrict__ out) {
  __shared__ __attribute__((aligned(16))) __bf16 q_sm[128 * 128];   // 32 KB
  __shared__ __attribute__((aligned(16))) __bf16 x_sm[128 * 128];   // 32 KB
  __shared__ __attribute__((aligned(16))) __bf16 A_lds[128 * 136];  // 34 KB
  int tid = threadIdx.x, lane = tid & 63, wave = tid >> 6;
  int wr = wave >> 1, wc = wave & 1;
  int l15 = lane & 15, qd = lane >> 4;
  int cb = blockIdx.x >> 2, dt = blockIdx.x & 3;
  int c = cb >> 3, b = cb & 7;
  const __bf16* qg = qb + ((long)c * 1024 + b) * 128;   // row stride 1024 elems
  const __bf16* kg = kbs + ((long)c * 1024 + b) * 128;
  const __bf16* vbase = vt + ((long)cb * 512 + dt * 128) * 128;  // contiguous
  const __bf16* sbase = St + ((long)cb * 512 + dt * 128) * 128;

  int rowoff = lane >> 4, sl = lane & 15;
#pragma unroll
  for (int it = 0; it < 8; ++it) {
    int rbase = it * 16 + wave * 4;
    int row = rbase + rowoff;
    int sg = (sl ^ (row & 15)) * 8;
    async_copy16(qg + (long)row * 1024 + sg, &q_sm[rbase * 128]);
    async_copy16(kg + (long)row * 1024 + sg, &x_sm[rbase * 128]);
  }
  __syncthreads();

  {
    f32x4 accA[4][4] = {};
#pragma unroll
    for (int kk = 0; kk < 4; ++kk) {
      bf16x8 af[4], bfr[4];
#pragma unroll
      for (int i = 0; i < 4; ++i) {
        int ra = wr * 64 + i * 16 + l15;
        af[i] = *(const bf16x8*)&q_sm[ra * 128 + (((kk * 4 + qd) ^ l15) & 15) * 8];
      }
#pragma unroll
      for (int j = 0; j < 4; ++j) {
        int rb = wc * 64 + j * 16 + l15;
        bfr[j] = *(const bf16x8*)&x_sm[rb * 128 + (((kk * 4 + qd) ^ l15) & 15) * 8];
      }
#pragma unroll
      for (int i = 0; i < 4; ++i)
#pragma unroll
        for (int j = 0; j < 4; ++j)
          accA[i][j] = __builtin_amdgcn_mfma_f32_16x16x32_bf16(af[i], bfr[j], accA[i][j], 0, 0, 0);
    }
#pragma unroll
    for (int i = 0; i < 4; ++i)
#pragma unroll
      for (int j = 0; j < 4; ++j) {
        int s = wc * 64 + j * 16 + l15;
#pragma unroll
        for (int r = 0; r < 4; ++r) {
          int t = wr * 64 + i * 16 + qd * 4 + r;
          A_lds[t * 136 + s] = (s <= t) ? (__bf16)accA[i][j][r] : (__bf16)0.f;
        }
      }
  }
  __syncthreads();   // P1 x_sm reads done + A visible

#pragma unroll
  for (int it = 0; it < 8; ++it) {
    int rbase = it * 16 + wave * 4;
    int row = rbase + rowoff;
    int sg = (sl ^ (row & 15)) * 8;
    async_copy16(vbase + (long)row * 128 + sg, &x_sm[rbase * 128]);
  }
  __syncthreads();

  f32x4 acc[4][4] = {};
#pragma unroll
  for (int kk = 0; kk < 4; ++kk) {
    int k0 = kk * 32;
    bf16x8 af[4], bfr[4];
#pragma unroll
    for (int i = 0; i < 4; ++i) {
      int ra = wr * 64 + i * 16 + l15;
      af[i] = *(const bf16x8*)&x_sm[ra * 128 + (((kk * 4 + qd) ^ l15) & 15) * 8];
    }
#pragma unroll
    for (int j = 0; j < 4; ++j)
      bfr[j] = *(const bf16x8*)&A_lds[(wc * 64 + j * 16 + l15) * 136 + k0 + qd * 8];
#pragma unroll
    for (int i = 0; i < 4; ++i)
#pragma unroll
      for (int j = 0; j < 4; ++j)
        acc[i][j] = __builtin_amdgcn_mfma_f32_16x16x32_bf16(af[i], bfr[j], acc[i][j], 0, 0, 0);
  }
  __syncthreads();   // P2 x_sm reads done

#pragma unroll
  for (int it = 0; it < 8; ++it) {
    int rbase = it * 16 + wave * 4;
    int row = rbase + rowoff;
    int sg = (sl ^ (row & 15)) * 8;
    async_copy16(sbase + (long)row * 128 + sg, &x_sm[rbase * 128]);
  }
  __syncthreads();

#pragma unroll
  for (int kk = 0; kk < 4; ++kk) {
    bf16x8 af[4], bfr[4];
#pragma unroll
    for (int i = 0; i < 4; ++i) {
      int ra = wr * 64 + i * 16 + l15;
      af[i] = *(const bf16x8*)&x_sm[ra * 128 + (((kk * 4 + qd) ^ l15) & 15) * 8];
    }
#pragma unroll
    for (int j = 0; j < 4; ++j) {
      int rb = wc * 64 + j * 16 + l15;
      bfr[j] = *(const bf16x8*)&q_sm[rb * 128 + (((kk * 4 + qd) ^ l15) & 15) * 8];
    }
#pragma unroll
    for (int i = 0; i < 4; ++i)
#pragma unroll
      for (int j = 0; j < 4; ++j)
        acc[i][j] = __builtin_amdgcn_mfma_f32_16x16x32_bf16(af[i], bfr[j], acc[i][j], 0, 0, 0);
  }

#pragma unroll
  for (int i = 0; i < 4; ++i)
#pragma unroll
    for (int j = 0; j < 4; ++j) {
      int colt = wc * 64 + j * 16 + l15;
      long addr = ((long)(c * 128 + colt) * 8 + b) * 512 + dt * 128 + wr * 64 + i * 16 + qd * 4;
      *(float4*)(out + addr) = *(float4*)&acc[i][j];
    }
}

extern "C" void kernel_launch(void* const* d_in, const int* in_sizes, int n_in,
                              void* d_out, int out_size, void* d_ws, size_t ws_size,
                              hipStream_t stream) {
  const float* x  = (const float*)d_in[0];
  const float* Wv = (const float*)d_in[1];
  const float* bv = (const float*)d_in[2];
  const float* Wk = (const float*)d_in[3];
  const float* bk = (const float*)d_in[4];
  const float* Wq = (const float*)d_in[5];
  const float* bq = (const float*)d_in[6];
  const float* Wa = (const float*)d_in[7];
  const float* ba = (const float*)d_in[8];
  float* out = (float*)d_out;
  float* ws = (float*)d_ws;

  float*  a_buf = ws;                          // 2,097,152 fl
  __bf16* qb    = (__bf16*)(ws + 2097152);     // 2,097,152 bf
  __bf16* kbs   = (__bf16*)(ws + 3145728);     // 2,097,152 bf
  __bf16* kt    = (__bf16*)(ws + 4194304);     // 2,097,152 bf
  __bf16* vt    = (__bf16*)(ws + 5242880);     // 8,388,608 bf
  __bf16* k_raw = (__bf16*)(ws + 9437184);     // 2,097,152 bf
  __bf16* q_raw = (__bf16*)(ws + 10485760);    // 2,097,152 bf
  __bf16* xb    = (__bf16*)(ws + 11534336);    // 8,388,608 bf
  __bf16* Wcat  = (__bf16*)(ws + 15728640);    // 458,752 bf
  __bf16* Gt    = xb;                          // overlay: xb dead after proj
  __bf16* St    = (__bf16*)(ws + 15958016);    // 8,388,608 bf
  float*  cpend = ws + 20152320;               // 16,384 fl

  conv_bf16<<<4096, 256, 0, stream>>>(x, xb);
  conv_w<<<224, 256, 0, stream>>>(Wv, Wk, Wq, Wa, Wcat);
  proj_mfma<<<dim3(128, 7), 256, 0, stream>>>(xb, Wcat, bv, bk, bq, ba,
                                              vt, k_raw, q_raw, a_buf);
  scan_cp<<<256, 512, 0, stream>>>(a_buf, k_raw, q_raw, kbs, qb, kt, cpend);
  gmm<<<512, 256, 0, stream>>>(vt, kt, cpend, Gt);
  scan_state<<<512, 256, 0, stream>>>(Gt, cpend, St);
  ymm<<<512, 256, 0, stream>>>(qb, kbs, vt, St, out);
}